// Round 10
// baseline (138.409 us; speedup 1.0000x reference)
//
#include <hip/hip_runtime.h>
#include <cstdint>
#include <utility>

#define NW 10
#define NL 4

// ============================================================================
// Round 10:
//  - CNOT rings tracked as compile-time GF(2) index maps (round 2).
//  - Lightcone: layer3 keeps Rot{1,5,9}, layer2 drops Rot(7) (round 2).
//  - Product-state init folds encoding RYs + all layer-0 Rots (round 3).
//  - DPP / ds_swizzle / ds_bpermute cross-lane exchange (rounds 4,6).
//  - Sample-pair v2 packing (round 7).
//  - NEW (a): v_permlane16/32_swap_b32 (gfx950 VALU lane exchange) for xor
//    masks 16/32/48 -> three cross gates + 2 reduction steps leave the DS
//    pipe (768 -> ~576 DS ops/wave-pair). DS-pipe floor ~60us -> ~45us.
//  - NEW (b): sched_barrier(0) every 8 slots in cross-lane gates caps the
//    scheduler's partner-fetch hoisting -> peak pressure ~112 regs, so the
//    state stays in arch VGPRs (rounds 7-9 pinned at ~87us from AGPR
//    round-trips; VGPR_Count 56-60 + occupancy 35% was the tell).
//  - NEW (c): __launch_bounds__(256,4): 128-reg budget, 4 waves/SIMD.
// ============================================================================

typedef float v2 __attribute__((ext_vector_type(2)));
typedef unsigned int u32x2 __attribute__((ext_vector_type(2)));

#if defined(__has_builtin)
#if __has_builtin(__builtin_amdgcn_permlane16_swap) && __has_builtin(__builtin_amdgcn_permlane32_swap)
#define HAVE_PERMLANE_SWAP 1
#endif
#endif

struct Plan {
    int n;
    uint16_t pmask[40];
    uint16_t rmask[40];
    uint8_t  lw[40];
    uint16_t measmask;
};

constexpr bool keep_rot(int l, int w) {
    if (l <= 1) return true;
    if (l == 2) return w != 7;
    return w == 1 || w == 5 || w == 9;   // l == 3
}

constexpr Plan make_plan() {
    Plan P{};
    unsigned row[10], cI[10];
    for (int b = 0; b < 10; ++b) { row[b] = 1u << b; cI[b] = 1u << b; }
    P.n = 0;
    for (int l = 0; l < NL; ++l) {
        for (int w = 0; w < NW; ++w) {
            if (l > 0 && keep_rot(l, w)) {          // layer-0 Rots folded into init
                const int b = 9 - w;                // wire w = state bit 9-w
                P.pmask[P.n] = (uint16_t)cI[b];
                P.rmask[P.n] = (uint16_t)row[b];
                P.lw[P.n]    = (uint8_t)(l * NW + w);
                P.n++;
            }
        }
        const int r = l % (NW - 1) + 1;
        for (int w = 0; w < NW; ++w) {              // ring: CNOT(w, (w+r)%10)
            const int cb = 9 - w, tb = 9 - ((w + r) % NW);
            row[tb] ^= row[cb];                     // M <- C * M
            cI[cb]  ^= cI[tb];                      // Minv <- Minv * C
        }
    }
    P.measmask = (uint16_t)row[0];                  // Z on virtual bit 0 (wire 9)
    return P;
}

constexpr Plan PL = make_plan();
constexpr int NROT = 22;
static_assert(PL.n == NROT, "plan size mismatch");

// ---------------------------------------------------------------------------
// cross-lane xor exchange on one 32-bit value, cheapest available engine:
//   masks 1,2,3 quad_perm DPP; 7 row_half_mirror; 15 row_mirror (VALU)
//   masks 16/32/48: v_permlane16/32_swap_b32 (VALU, gfx950)
//   other masks <32: ds_swizzle ; else: ds_bpermute (DS pipe)
// ---------------------------------------------------------------------------
template<int MASK>
__device__ __forceinline__ float swz(float v, int lane) {
    if constexpr (MASK == 1) {        // quad_perm [1,0,3,2]
        return __int_as_float(__builtin_amdgcn_mov_dpp(__float_as_int(v), 0xB1, 0xF, 0xF, true));
    } else if constexpr (MASK == 2) { // quad_perm [2,3,0,1]
        return __int_as_float(__builtin_amdgcn_mov_dpp(__float_as_int(v), 0x4E, 0xF, 0xF, true));
    } else if constexpr (MASK == 3) { // quad_perm [3,2,1,0]
        return __int_as_float(__builtin_amdgcn_mov_dpp(__float_as_int(v), 0x1B, 0xF, 0xF, true));
    } else if constexpr (MASK == 7) { // row_half_mirror
        return __int_as_float(__builtin_amdgcn_mov_dpp(__float_as_int(v), 0x141, 0xF, 0xF, true));
    } else if constexpr (MASK == 15) { // row_mirror
        return __int_as_float(__builtin_amdgcn_mov_dpp(__float_as_int(v), 0x140, 0xF, 0xF, true));
    }
#ifdef HAVE_PERMLANE_SWAP
    else if constexpr (MASK == 16) {
        // r.x = [x0-15,x0-15,x32-47,x32-47]; r.y = [x16-31,x16-31,x48-63,x48-63]
        const u32x2 r = __builtin_amdgcn_permlane16_swap(__float_as_uint(v), __float_as_uint(v), false, false);
        return __uint_as_float((lane & 16) ? r.x : r.y);
    } else if constexpr (MASK == 32) {
        // r.x = [lo32,lo32]; r.y = [hi32,hi32]
        const u32x2 r = __builtin_amdgcn_permlane32_swap(__float_as_uint(v), __float_as_uint(v), false, false);
        return __uint_as_float((lane & 32) ? r.x : r.y);
    } else if constexpr (MASK == 48) {
        const u32x2 r = __builtin_amdgcn_permlane32_swap(__float_as_uint(v), __float_as_uint(v), false, false);
        const unsigned t = (lane & 32) ? r.x : r.y;                  // x[lane^32]
        const u32x2 r2 = __builtin_amdgcn_permlane16_swap(t, t, false, false);
        return __uint_as_float((lane & 16) ? r2.x : r2.y);           // x[lane^48]
    }
#endif
    else if constexpr (MASK < 32) {
        return __int_as_float(__builtin_amdgcn_ds_swizzle(
            __float_as_int(v), (MASK << 10) | 0x1F));       // bit-mode xor pattern
    } else {
        return __int_as_float(__builtin_amdgcn_ds_bpermute(
            (lane << 2) ^ (MASK << 2), __float_as_int(v)));
    }
}

template<int MASK>
__device__ __forceinline__ v2 swz2(v2 v, int lane) {
    v2 r;
    r.x = swz<MASK>(v.x, lane);
    r.y = swz<MASK>(v.y, lane);
    return r;
}

__device__ __forceinline__ v2 mkv2(float a, float b) { v2 r; r.x = a; r.y = b; return r; }

__device__ __forceinline__ void cmul2(v2 ar, v2 ai, v2 br, v2 bi, v2& cr, v2& ci) {
    cr = ar * br - ai * bi;
    ci = ar * bi + ai * br;
}

// single amplitude-pair update; S (slot-role parity) folds at compile time
// after unrolling. bmi/bor already carry the lane-role sign.
__device__ __forceinline__ void upd(v2& xr, v2& xi, v2 pr, v2 pi,
                                    float cmr, float coi, float bmi, float bor,
                                    bool S) {
    const float emi = S ? -bmi : bmi;
    const float eor = S ? -bor : bor;
    const v2 nr = cmr * xr - emi * xi + eor * pr - coi * pi;
    const v2 ni = cmr * xi + emi * xr + eor * pi + coi * pr;
    xr = nr; xi = ni;
}

// one masked-pair rotation; SU(2): u11=conj(u00), u10=-conj(u01).
// state: sr[j]/si[j] = v2{sample0, sample1} for local slot j.
template<int G>
__device__ __forceinline__ void apply_rot(v2 (&sr)[16], v2 (&si)[16],
                                          const float4* __restrict__ rotm,
                                          int lane) {
    constexpr unsigned pm = PL.pmask[G], rm = PL.rmask[G];
    constexpr int pLoc = pm & 15, pLane = (int)(pm >> 4);
    constexpr int rLoc = rm & 15, rLane = (int)(rm >> 4);
    const float4 m = rotm[PL.lw[G]];
    const bool rl = (__popc(lane & rLane) & 1) != 0;   // lane part of role
    const float cmr = m.x, coi = m.w;
    const float bmi = rl ? -m.y : m.y;
    const float bor = rl ? -m.z : m.z;

    if constexpr (pLane == 0) {
        // fully local pair (j, j^pLoc): register-only, no barriers needed
#pragma unroll
        for (int j = 0; j < 16; ++j) {
            const int k = j ^ pLoc;
            if (j < k) {
                const v2 ajr = sr[j], aji = si[j];
                const v2 akr = sr[k], aki = si[k];
                upd(sr[j], si[j], akr, aki, cmr, coi, bmi, bor,
                    (__builtin_popcount(j & rLoc) & 1) != 0);
                upd(sr[k], si[k], ajr, aji, cmr, coi, bmi, bor,
                    (__builtin_popcount(k & rLoc) & 1) != 0);
            }
        }
    } else if constexpr (pLoc == 0) {
        // partner = same slot, other lane; barrier every 8 slots caps the
        // scheduler's partner-fetch hoisting (register-pressure control)
#pragma unroll
        for (int j = 0; j < 16; ++j) {
            const v2 pr = swz2<pLane>(sr[j], lane);
            const v2 pi = swz2<pLane>(si[j], lane);
            upd(sr[j], si[j], pr, pi, cmr, coi, bmi, bor,
                (__builtin_popcount(j & rLoc) & 1) != 0);
            if (j == 7 || j == 15) __builtin_amdgcn_sched_barrier(0);
        }
    } else {
        // partner = slot j^pLoc at lane^pLane
#pragma unroll
        for (int j = 0; j < 16; ++j) {
            const int k = j ^ pLoc;
            if (j < k) {
                const v2 pjr = swz2<pLane>(sr[k], lane);
                const v2 pji = swz2<pLane>(si[k], lane);
                const v2 pkr = swz2<pLane>(sr[j], lane);
                const v2 pki = swz2<pLane>(si[j], lane);
                upd(sr[j], si[j], pjr, pji, cmr, coi, bmi, bor,
                    (__builtin_popcount(j & rLoc) & 1) != 0);
                upd(sr[k], si[k], pkr, pki, cmr, coi, bmi, bor,
                    (__builtin_popcount(k & rLoc) & 1) != 0);
            }
            if (j == 7 || j == 15) __builtin_amdgcn_sched_barrier(0);
        }
    }
}

template<int... Gs>
__device__ __forceinline__ void apply_all(v2 (&sr)[16], v2 (&si)[16],
                                          const float4* __restrict__ rotm,
                                          int lane,
                                          std::integer_sequence<int, Gs...>) {
    (apply_rot<Gs>(sr, si, rotm, lane), ...);
}

// 256 threads, min 4 waves/EU -> 128-reg budget. sched_barriers cap peak
// pressure to ~112 regs so the state stays in arch VGPRs (no AGPR churn).
__global__ __launch_bounds__(256, 4) void vqc_kernel(const float* __restrict__ X,
                                                     const float* __restrict__ W,
                                                     const float* __restrict__ bias,
                                                     float* __restrict__ out,
                                                     int n_pairs) {
    __shared__ float4 rotm[NL * NW];
    const int t = threadIdx.x;

    // per-block Rot coefficient prep: only m00, m01 needed (SU(2))
    if (t < NL * NW) {
        const float phi = W[t * 3 + 0], th = W[t * 3 + 1], om = W[t * 3 + 2];
        float sh, ch; sincosf(0.5f * th, &sh, &ch);
        float s0, c0; sincosf(-0.5f * (phi + om), &s0, &c0);   // e^{-i(phi+om)/2}
        float s1, c1; sincosf( 0.5f * (phi - om), &s1, &c1);   // e^{+i(phi-om)/2}
        rotm[t] = make_float4(c0 * ch, s0 * ch, -c1 * sh, -s1 * sh);
    }
    __syncthreads();

    const int wave = (blockIdx.x * blockDim.x + t) >> 6;   // one wave per SAMPLE PAIR
    const int lane = t & 63;
    if (wave >= n_pairs) return;

    // ---- product-state init for both samples: v_w = Rot0_w * RY(x_w*pi/2)|0> ----
    const float* xp = X + (size_t)(2 * wave) * NW;        // sample0; sample1 at +NW

    // running lane-product H over wires 0..5 (wire w -> lane bit 5-w)
    v2 hr, hi;
#pragma unroll
    for (int w = 0; w < 6; ++w) {
        float s0, c0, s1, c1;
        __sincosf(xp[w]      * 0.78539816339744831f, &s0, &c0);
        __sincosf(xp[w + NW] * 0.78539816339744831f, &s1, &c1);
        const v2 s = mkv2(s0, s1), c = mkv2(c0, c1);
        const float4 m = rotm[w];                          // layer 0
        const v2 a0r = m.x * c + m.z * s;
        const v2 a0i = m.y * c + m.w * s;
        const v2 a1r = m.x * s - m.z * c;
        const v2 a1i = m.w * c - m.y * s;
        const bool b = (lane >> (5 - w)) & 1;
        const v2 br = b ? a1r : a0r;
        const v2 bi = b ? a1i : a0i;
        if (w == 0) { hr = br; hi = bi; }
        else {
            v2 nr, ni; cmul2(hr, hi, br, bi, nr, ni);
            hr = nr; hi = ni;
        }
    }
    // wires 6..9 kept for local tables
    v2 t0r[4], t0i[4], t1r[4], t1i[4];
#pragma unroll
    for (int w = 6; w < 10; ++w) {
        float s0, c0, s1, c1;
        __sincosf(xp[w]      * 0.78539816339744831f, &s0, &c0);
        __sincosf(xp[w + NW] * 0.78539816339744831f, &s1, &c1);
        const v2 s = mkv2(s0, s1), c = mkv2(c0, c1);
        const float4 m = rotm[w];
        t0r[w - 6] = m.x * c + m.z * s;
        t0i[w - 6] = m.y * c + m.w * s;
        t1r[w - 6] = m.x * s - m.z * c;
        t1i[w - 6] = m.w * c - m.y * s;
    }
    // A over wires 6,7 (j bits 3,2), B over wires 8,9 (j bits 1,0)
    v2 Ar[4], Ai[4], Br[4], Bi[4];
#pragma unroll
    for (int u = 0; u < 4; ++u) {
        const int hb = (u >> 1) & 1, lb = u & 1;
        cmul2(hb ? t1r[0] : t0r[0], hb ? t1i[0] : t0i[0],
              lb ? t1r[1] : t0r[1], lb ? t1i[1] : t0i[1], Ar[u], Ai[u]);
        cmul2(hb ? t1r[2] : t0r[2], hb ? t1i[2] : t0i[2],
              lb ? t1r[3] : t0r[3], lb ? t1i[3] : t0i[3], Br[u], Bi[u]);
    }
    // HA = H*A, then state[j] = HA[j>>2] * B[j&3]
    v2 HAr[4], HAi[4];
#pragma unroll
    for (int u = 0; u < 4; ++u) cmul2(hr, hi, Ar[u], Ai[u], HAr[u], HAi[u]);

    v2 sr[16], si[16];
#pragma unroll
    for (int j = 0; j < 16; ++j) {
        cmul2(HAr[j >> 2], HAi[j >> 2], Br[j & 3], Bi[j & 3], sr[j], si[j]);
    }

    // ---- 22 surviving rotations (layers 1..3); CNOTs are index-map updates ----
    apply_all(sr, si, rotm, lane, std::make_integer_sequence<int, NROT>{});

    // ---- measurement: sign = parity(j_full & measmask) ----
    constexpr unsigned mm = PL.measmask;
    constexpr int mLoc = mm & 15, mLane = (int)(mm >> 4);
    v2 acc = mkv2(0.0f, 0.0f);
#pragma unroll
    for (int j = 0; j < 16; ++j) {
        const v2 p = sr[j] * sr[j] + si[j] * si[j];
        if (__builtin_popcount(j & mLoc) & 1) acc -= p; else acc += p;
    }
    if (__popc(lane & mLane) & 1) acc = -acc;
    acc += swz2<1>(acc, lane);
    acc += swz2<2>(acc, lane);
    acc += swz2<4>(acc, lane);
    acc += swz2<8>(acc, lane);
    acc += swz2<16>(acc, lane);
    acc += swz2<32>(acc, lane);
    if (lane == 0) {
        const float b0 = bias[0];
        out[2 * wave]     = acc.x + b0;
        out[2 * wave + 1] = acc.y + b0;
    }
}

extern "C" void kernel_launch(void* const* d_in, const int* in_sizes, int n_in,
                              void* d_out, int out_size, void* d_ws, size_t ws_size,
                              hipStream_t stream) {
    const float* X    = (const float*)d_in[0];
    const float* W    = (const float*)d_in[1];
    const float* bias = (const float*)d_in[2];
    float* out = (float*)d_out;
    const int n_samples = in_sizes[0] / NW;               // 16384
    const int n_pairs = n_samples / 2;                    // 8192 (even batch)
    const int threads = 256;                              // 4 waves/block
    const int blocks = (n_pairs * 64 + threads - 1) / threads;
    hipLaunchKernelGGL(vqc_kernel, dim3(blocks), dim3(threads), 0, stream,
                       X, W, bias, out, n_pairs);
}

// Round 11
// 126.825 us; speedup vs baseline: 1.0913x; 1.0913x over previous
//
#include <hip/hip_runtime.h>
#include <cstdint>
#include <utility>

#define NW 10
#define NL 4

// ============================================================================
// Round 11:
//  - CNOT rings tracked as compile-time GF(2) index maps (round 2).
//  - Lightcone: layer3 keeps Rot{1,5,9}, layer2 drops Rot(7) (round 2).
//  - Product-state init folds encoding RYs + all layer-0 Rots (round 3).
//  - DPP / ds_swizzle / ds_bpermute cross-lane exchange (rounds 4,6).
//  - Sample-pair v2 packing (round 7), __launch_bounds__(256,2) (round 9).
//  - Reverted: permlane-swap + sched_barrier (round 10 regression).
//  - NEW: static GF(2) basis relabeling T (logical index -> physical slot)
//    chosen so gate pair-masks land on DPP-able lane-xor patterns
//    {1,2,3,7,15} or fully-local: 12 DS / 7 DPP / 3 local becomes
//    9 DS / 9 DPP / 4 local  (DS ops/wave-pair 776 -> 584).
//    T is block-structured (slot bits identity), so init changes only the
//    six lane-bit selects into lane-parity selects. Role & measurement
//    masks transform via rows of T^{-1} (constexpr GF(2) elimination).
// ============================================================================

typedef float v2 __attribute__((ext_vector_type(2)));

// ---- compile-time GF(2) relabeling ----------------------------------------
struct Cols10 { unsigned c[10]; };
struct Rows10 { unsigned r[10]; };

// T columns: image of logical bit b in physical bits. Slot bits 0..3 identity;
// lane images chosen (see derivation) to DPP-ify 9 cross gates.
constexpr Cols10 TMAT = {{
    0x001, 0x002, 0x004, 0x008,                  // logical 0..3 -> slot bits
    0x070, 0x080, 0x100, 0x130, 0x210, 0x200     // logical 4..9 -> lane mixes
}};

constexpr unsigned tmap(unsigned m) {            // pair-mask transform (columns)
    unsigned r = 0;
    for (int b = 0; b < 10; ++b) if ((m >> b) & 1u) r ^= TMAT.c[b];
    return r;
}

constexpr Rows10 invertT() {                     // rows of T^{-1} over phys bits
    unsigned a[10] = {}, inv[10] = {};
    for (int i = 0; i < 10; ++i) {
        for (int j = 0; j < 10; ++j) a[i] |= ((TMAT.c[j] >> i) & 1u) << j;
        inv[i] = 1u << i;
    }
    for (int col = 0; col < 10; ++col) {
        int piv = -1;
        for (int r2 = col; r2 < 10; ++r2) if ((a[r2] >> col) & 1u) { piv = r2; break; }
        unsigned ta = a[piv]; a[piv] = a[col]; a[col] = ta;
        unsigned ti = inv[piv]; inv[piv] = inv[col]; inv[col] = ti;
        for (int r2 = 0; r2 < 10; ++r2)
            if (r2 != col && ((a[r2] >> col) & 1u)) { a[r2] ^= a[col]; inv[r2] ^= inv[col]; }
    }
    Rows10 R{};
    for (int i = 0; i < 10; ++i) R.r[i] = inv[i];
    return R;
}
constexpr Rows10 RROW = invertT();

constexpr unsigned rmap(unsigned rowmask) {      // role/meas row-vector transform
    unsigned r = 0;
    for (int b = 0; b < 10; ++b) if ((rowmask >> b) & 1u) r ^= RROW.r[b];
    return r;
}

// sanity: block structure holds (slot rows identity, lane rows slot-free)
static_assert(RROW.r[0] == 1 && RROW.r[1] == 2 && RROW.r[2] == 4 && RROW.r[3] == 8, "slot rows");
static_assert((RROW.r[4] & 15) == 0 && (RROW.r[5] & 15) == 0 && (RROW.r[6] & 15) == 0 &&
              (RROW.r[7] & 15) == 0 && (RROW.r[8] & 15) == 0 && (RROW.r[9] & 15) == 0, "lane rows");

struct Plan {
    int n;
    uint16_t pmask[40];
    uint16_t rmask[40];
    uint8_t  lw[40];
    uint16_t measmask;
};

constexpr bool keep_rot(int l, int w) {
    if (l <= 1) return true;
    if (l == 2) return w != 7;
    return w == 1 || w == 5 || w == 9;   // l == 3
}

constexpr Plan make_plan() {
    Plan P{};
    unsigned row[10], cI[10];
    for (int b = 0; b < 10; ++b) { row[b] = 1u << b; cI[b] = 1u << b; }
    P.n = 0;
    for (int l = 0; l < NL; ++l) {
        for (int w = 0; w < NW; ++w) {
            if (l > 0 && keep_rot(l, w)) {          // layer-0 Rots folded into init
                const int b = 9 - w;                // wire w = logical bit 9-w
                P.pmask[P.n] = (uint16_t)tmap(cI[b]);   // physical pair mask
                P.rmask[P.n] = (uint16_t)rmap(row[b]);  // physical role mask
                P.lw[P.n]    = (uint8_t)(l * NW + w);
                P.n++;
            }
        }
        const int r = l % (NW - 1) + 1;
        for (int w = 0; w < NW; ++w) {              // ring: CNOT(w, (w+r)%10)
            const int cb = 9 - w, tb = 9 - ((w + r) % NW);
            row[tb] ^= row[cb];                     // M <- C * M
            cI[cb]  ^= cI[tb];                      // Minv <- Minv * C
        }
    }
    P.measmask = (uint16_t)rmap(row[0]);            // Z on virtual bit 0 (wire 9)
    return P;
}

constexpr Plan PL = make_plan();
constexpr int NROT = 22;
static_assert(PL.n == NROT, "plan size mismatch");

// init lane-parity selects for wires 0..5 (logical bits 9..4)
constexpr int LSEL[6] = {
    (int)(RROW.r[9] >> 4), (int)(RROW.r[8] >> 4), (int)(RROW.r[7] >> 4),
    (int)(RROW.r[6] >> 4), (int)(RROW.r[5] >> 4), (int)(RROW.r[4] >> 4)
};

// ---------------------------------------------------------------------------
// cross-lane xor exchange on one 32-bit value:
//   masks 1,2,3 quad_perm DPP; 7 row_half_mirror; 15 row_mirror (VALU pipe)
//   other masks <32: ds_swizzle ; >=32: ds_bpermute (DS pipe)
// ---------------------------------------------------------------------------
template<int MASK>
__device__ __forceinline__ float swz(float v, int lane) {
    if constexpr (MASK == 1) {        // quad_perm [1,0,3,2]
        return __int_as_float(__builtin_amdgcn_mov_dpp(__float_as_int(v), 0xB1, 0xF, 0xF, true));
    } else if constexpr (MASK == 2) { // quad_perm [2,3,0,1]
        return __int_as_float(__builtin_amdgcn_mov_dpp(__float_as_int(v), 0x4E, 0xF, 0xF, true));
    } else if constexpr (MASK == 3) { // quad_perm [3,2,1,0]
        return __int_as_float(__builtin_amdgcn_mov_dpp(__float_as_int(v), 0x1B, 0xF, 0xF, true));
    } else if constexpr (MASK == 7) { // row_half_mirror
        return __int_as_float(__builtin_amdgcn_mov_dpp(__float_as_int(v), 0x141, 0xF, 0xF, true));
    } else if constexpr (MASK == 15) { // row_mirror
        return __int_as_float(__builtin_amdgcn_mov_dpp(__float_as_int(v), 0x140, 0xF, 0xF, true));
    } else if constexpr (MASK < 32) {
        return __int_as_float(__builtin_amdgcn_ds_swizzle(
            __float_as_int(v), (MASK << 10) | 0x1F));       // bit-mode xor pattern
    } else {
        return __int_as_float(__builtin_amdgcn_ds_bpermute(
            (lane << 2) ^ (MASK << 2), __float_as_int(v)));
    }
}

template<int MASK>
__device__ __forceinline__ v2 swz2(v2 v, int lane) {
    v2 r;
    r.x = swz<MASK>(v.x, lane);
    r.y = swz<MASK>(v.y, lane);
    return r;
}

__device__ __forceinline__ v2 mkv2(float a, float b) { v2 r; r.x = a; r.y = b; return r; }

__device__ __forceinline__ void cmul2(v2 ar, v2 ai, v2 br, v2 bi, v2& cr, v2& ci) {
    cr = ar * br - ai * bi;
    ci = ar * bi + ai * br;
}

// single amplitude-pair update; S (slot-role parity) folds at compile time.
__device__ __forceinline__ void upd(v2& xr, v2& xi, v2 pr, v2 pi,
                                    float cmr, float coi, float bmi, float bor,
                                    bool S) {
    const float emi = S ? -bmi : bmi;
    const float eor = S ? -bor : bor;
    const v2 nr = cmr * xr - emi * xi + eor * pr - coi * pi;
    const v2 ni = cmr * xi + emi * xr + eor * pi + coi * pr;
    xr = nr; xi = ni;
}

// one masked-pair rotation; SU(2): u11=conj(u00), u10=-conj(u01).
template<int G>
__device__ __forceinline__ void apply_rot(v2 (&sr)[16], v2 (&si)[16],
                                          const float4* __restrict__ rotm,
                                          int lane) {
    constexpr unsigned pm = PL.pmask[G], rm = PL.rmask[G];
    constexpr int pLoc = pm & 15, pLane = (int)(pm >> 4);
    constexpr int rLoc = rm & 15, rLane = (int)(rm >> 4);
    const float4 m = rotm[PL.lw[G]];
    const bool rl = (__popc(lane & rLane) & 1) != 0;   // lane part of role
    const float cmr = m.x, coi = m.w;
    const float bmi = rl ? -m.y : m.y;
    const float bor = rl ? -m.z : m.z;

    if constexpr (pLane == 0) {
        // fully local pair (j, j^pLoc)
#pragma unroll
        for (int j = 0; j < 16; ++j) {
            const int k = j ^ pLoc;
            if (j < k) {
                const v2 ajr = sr[j], aji = si[j];
                const v2 akr = sr[k], aki = si[k];
                upd(sr[j], si[j], akr, aki, cmr, coi, bmi, bor,
                    (__builtin_popcount(j & rLoc) & 1) != 0);
                upd(sr[k], si[k], ajr, aji, cmr, coi, bmi, bor,
                    (__builtin_popcount(k & rLoc) & 1) != 0);
            }
        }
    } else if constexpr (pLoc == 0) {
        // partner = same slot, other lane
#pragma unroll
        for (int j = 0; j < 16; ++j) {
            const v2 pr = swz2<pLane>(sr[j], lane);
            const v2 pi = swz2<pLane>(si[j], lane);
            upd(sr[j], si[j], pr, pi, cmr, coi, bmi, bor,
                (__builtin_popcount(j & rLoc) & 1) != 0);
        }
    } else {
        // partner = slot j^pLoc at lane^pLane
#pragma unroll
        for (int j = 0; j < 16; ++j) {
            const int k = j ^ pLoc;
            if (j < k) {
                const v2 pjr = swz2<pLane>(sr[k], lane);
                const v2 pji = swz2<pLane>(si[k], lane);
                const v2 pkr = swz2<pLane>(sr[j], lane);
                const v2 pki = swz2<pLane>(si[j], lane);
                upd(sr[j], si[j], pjr, pji, cmr, coi, bmi, bor,
                    (__builtin_popcount(j & rLoc) & 1) != 0);
                upd(sr[k], si[k], pkr, pki, cmr, coi, bmi, bor,
                    (__builtin_popcount(k & rLoc) & 1) != 0);
            }
        }
    }
}

template<int... Gs>
__device__ __forceinline__ void apply_all(v2 (&sr)[16], v2 (&si)[16],
                                          const float4* __restrict__ rotm,
                                          int lane,
                                          std::integer_sequence<int, Gs...>) {
    (apply_rot<Gs>(sr, si, rotm, lane), ...);
}

__global__ __launch_bounds__(256, 2) void vqc_kernel(const float* __restrict__ X,
                                                     const float* __restrict__ W,
                                                     const float* __restrict__ bias,
                                                     float* __restrict__ out,
                                                     int n_pairs) {
    __shared__ float4 rotm[NL * NW];
    const int t = threadIdx.x;

    // per-block Rot coefficient prep: only m00, m01 needed (SU(2))
    if (t < NL * NW) {
        const float phi = W[t * 3 + 0], th = W[t * 3 + 1], om = W[t * 3 + 2];
        float sh, ch; sincosf(0.5f * th, &sh, &ch);
        float s0, c0; sincosf(-0.5f * (phi + om), &s0, &c0);   // e^{-i(phi+om)/2}
        float s1, c1; sincosf( 0.5f * (phi - om), &s1, &c1);   // e^{+i(phi-om)/2}
        rotm[t] = make_float4(c0 * ch, s0 * ch, -c1 * sh, -s1 * sh);
    }
    __syncthreads();

    const int wave = (blockIdx.x * blockDim.x + t) >> 6;   // one wave per SAMPLE PAIR
    const int lane = t & 63;
    if (wave >= n_pairs) return;

    // ---- product-state init for both samples: v_w = Rot0_w * RY(x_w*pi/2)|0> ----
    // amplitude at physical p = psi_{R(p)}: lane wires select via parity masks
    const float* xp = X + (size_t)(2 * wave) * NW;        // sample0; sample1 at +NW

    // running lane-product H over wires 0..5 (parity-select per relabeling)
    v2 hr, hi;
#pragma unroll
    for (int w = 0; w < 6; ++w) {
        float s0, c0, s1, c1;
        __sincosf(xp[w]      * 0.78539816339744831f, &s0, &c0);
        __sincosf(xp[w + NW] * 0.78539816339744831f, &s1, &c1);
        const v2 s = mkv2(s0, s1), c = mkv2(c0, c1);
        const float4 m = rotm[w];                          // layer 0
        const v2 a0r = m.x * c + m.z * s;
        const v2 a0i = m.y * c + m.w * s;
        const v2 a1r = m.x * s - m.z * c;
        const v2 a1i = m.w * c - m.y * s;
        const bool b = (__popc(lane & LSEL[w]) & 1) != 0;
        const v2 br = b ? a1r : a0r;
        const v2 bi = b ? a1i : a0i;
        if (w == 0) { hr = br; hi = bi; }
        else {
            v2 nr, ni; cmul2(hr, hi, br, bi, nr, ni);
            hr = nr; hi = ni;
        }
    }
    // wires 6..9 (slot bits identity under T): local tables
    v2 t0r[4], t0i[4], t1r[4], t1i[4];
#pragma unroll
    for (int w = 6; w < 10; ++w) {
        float s0, c0, s1, c1;
        __sincosf(xp[w]      * 0.78539816339744831f, &s0, &c0);
        __sincosf(xp[w + NW] * 0.78539816339744831f, &s1, &c1);
        const v2 s = mkv2(s0, s1), c = mkv2(c0, c1);
        const float4 m = rotm[w];
        t0r[w - 6] = m.x * c + m.z * s;
        t0i[w - 6] = m.y * c + m.w * s;
        t1r[w - 6] = m.x * s - m.z * c;
        t1i[w - 6] = m.w * c - m.y * s;
    }
    // A over wires 6,7 (slot bits 3,2), B over wires 8,9 (slot bits 1,0)
    v2 Ar[4], Ai[4], Br[4], Bi[4];
#pragma unroll
    for (int u = 0; u < 4; ++u) {
        const int hb = (u >> 1) & 1, lb = u & 1;
        cmul2(hb ? t1r[0] : t0r[0], hb ? t1i[0] : t0i[0],
              lb ? t1r[1] : t0r[1], lb ? t1i[1] : t0i[1], Ar[u], Ai[u]);
        cmul2(hb ? t1r[2] : t0r[2], hb ? t1i[2] : t0i[2],
              lb ? t1r[3] : t0r[3], lb ? t1i[3] : t0i[3], Br[u], Bi[u]);
    }
    // HA = H*A, then state[j] = HA[j>>2] * B[j&3]
    v2 HAr[4], HAi[4];
#pragma unroll
    for (int u = 0; u < 4; ++u) cmul2(hr, hi, Ar[u], Ai[u], HAr[u], HAi[u]);

    v2 sr[16], si[16];
#pragma unroll
    for (int j = 0; j < 16; ++j) {
        cmul2(HAr[j >> 2], HAi[j >> 2], Br[j & 3], Bi[j & 3], sr[j], si[j]);
    }

    // ---- 22 surviving rotations (layers 1..3); CNOTs are index-map updates ----
    apply_all(sr, si, rotm, lane, std::make_integer_sequence<int, NROT>{});

    // ---- measurement: sign = parity(p & measmask_phys) ----
    constexpr unsigned mm = PL.measmask;
    constexpr int mLoc = mm & 15, mLane = (int)(mm >> 4);
    v2 acc = mkv2(0.0f, 0.0f);
#pragma unroll
    for (int j = 0; j < 16; ++j) {
        const v2 p = sr[j] * sr[j] + si[j] * si[j];
        if (__builtin_popcount(j & mLoc) & 1) acc -= p; else acc += p;
    }
    if (__popc(lane & mLane) & 1) acc = -acc;
    acc += swz2<1>(acc, lane);
    acc += swz2<2>(acc, lane);
    acc += swz2<4>(acc, lane);
    acc += swz2<8>(acc, lane);
    acc += swz2<16>(acc, lane);
    acc += swz2<32>(acc, lane);
    if (lane == 0) {
        const float b0 = bias[0];
        out[2 * wave]     = acc.x + b0;
        out[2 * wave + 1] = acc.y + b0;
    }
}

extern "C" void kernel_launch(void* const* d_in, const int* in_sizes, int n_in,
                              void* d_out, int out_size, void* d_ws, size_t ws_size,
                              hipStream_t stream) {
    const float* X    = (const float*)d_in[0];
    const float* W    = (const float*)d_in[1];
    const float* bias = (const float*)d_in[2];
    float* out = (float*)d_out;
    const int n_samples = in_sizes[0] / NW;               // 16384
    const int n_pairs = n_samples / 2;                    // 8192 (even batch)
    const int threads = 256;                              // 4 waves/block
    const int blocks = (n_pairs * 64 + threads - 1) / threads;
    hipLaunchKernelGGL(vqc_kernel, dim3(blocks), dim3(threads), 0, stream,
                       X, W, bias, out, n_pairs);
}